// Round 10
// baseline (7952.258 us; speedup 1.0000x reference)
//
#include <hip/hip_runtime.h>
#include <hip/hip_cooperative_groups.h>

namespace cg = cooperative_groups;

// GlobalNet conv-GRU on MI355X — round 10.
// r5-r9 post-mortem: body-level changes (B traffic, TLP, ILP, K-split) all land
// within +-10% of r5 => the invariant is the 64 serial launches (~8 us gap/step)
// + per-step hb restage + hf global round-trip. Fix: ONE persistent cooperative
// kernel (256 blocks = 1/CU, r5's 10-wave body), t-loop inside, grid.sync()
// between steps. h state (fp32 + bf16 A-window dbuf) lives in LDS; only 4
// boundary rows/block/step cross global.

#define Bn   16
#define Tn   64
#define Ln   512
#define Cn   64
#define Hn   150
#define G3   450
#define SW   160
#define HP   160    // padded hidden
#define KCH  25     // k-chunks (32) for h GEMM (K=800)
#define KCX  10     // k-chunks for x GEMM (K=320)
#define Mtot 8192   // Bn*Ln

typedef __bf16 bf16x8 __attribute__((ext_vector_type(8)));
typedef float  f32x4  __attribute__((ext_vector_type(4)));
typedef short  s16x4  __attribute__((ext_vector_type(4)));

#define MFMA_B16(a, b, c) __builtin_amdgcn_mfma_f32_16x16x32_bf16((a), (b), (c), 0, 0, 0)

__device__ inline short f2bf(float f) {
  unsigned u = __builtin_bit_cast(unsigned, f);
  u += 0x7fffu + ((u >> 16) & 1u);   // RNE (finite inputs)
  return (short)(u >> 16);
}

// Packed B layout: [nt (n/16)][kc][lane (quad*16+l16)][j (8)] shorts.
// Fragment element: B[k = kc*32+quad*8+j][n = nt*16+l16].
// n maps (seg=n/160, jl=n%160) -> orig col seg*150+jl (zero pad elsewhere).
__global__ __launch_bounds__(256) void pack_weights(const float* __restrict__ ki,
                                                    const float* __restrict__ kh,
                                                    short* __restrict__ Bx,
                                                    short* __restrict__ Bh) {
  int idx = blockIdx.x * 256 + threadIdx.x;
  if (idx < 32 * KCH * 512) {
    int j = idx & 7, lane = (idx >> 3) & 63;
    int rest = idx >> 9;
    int kc = rest % KCH, nt = rest / KCH;
    int quad = lane >> 4, l16 = lane & 15;
    int n = nt * 16 + l16, seg = n / SW, jl = n - seg * SW;
    int kk = kc / 5, jj = (kc - kk * 5) * 32 + quad * 8 + j;
    float v = (seg < 3 && jl < Hn && jj < Hn) ? kh[(kk * Hn + jj) * G3 + seg * Hn + jl] : 0.f;
    Bh[idx] = f2bf(v);
  } else {
    int r = idx - 32 * KCH * 512;
    if (r < 32 * KCX * 512) {
      int j = r & 7, lane = (r >> 3) & 63;
      int rest = r >> 9;
      int kc = rest % KCX, nt = rest / KCX;
      int quad = lane >> 4, l16 = lane & 15;
      int n = nt * 16 + l16, seg = n / SW, jl = n - seg * SW;
      int kk = kc / 2, cc = (kc - kk * 2) * 32 + quad * 8 + j;
      float v = (seg < 3 && jl < Hn) ? ki[(kk * Cn + cc) * G3 + seg * Hn + jl] : 0.f;
      Bx[r] = f2bf(v);
    }
  }
}

// Persistent cooperative scan. Grid 256 (= 1 block/CU): block = (batch bb,
// 32-row chunk l0). 640 threads = 10 waves; wave w = j-tile jt in 0..9 covers
// 2 m-frags x 3 segment n-tiles {jt, jt+10, jt+20} + axn.
// LDS state across t: ah[2] bf16 A-window dbuf (rows l0-2..l0+33), hfl fp32 h.
// Per step only 4 boundary rows go through global hbG (grid.sync ordered).
__global__ __launch_bounds__(640)
void gru_scan(const float* __restrict__ xs, const short* __restrict__ Bh,
              const short* __restrict__ Bx, short* __restrict__ hbG,
              float* __restrict__ hfG) {
  __shared__ short ah[2][36 * 168];   // 24.2 KB
  __shared__ short ax[36 * 72];       // 5.2 KB
  __shared__ float hfl[32 * 150];     // 19.2 KB
  cg::grid_group grid = cg::this_grid();

  const int tid = threadIdx.x;
  const int bb  = blockIdx.x >> 4;
  const int l0  = (blockIdx.x & 15) * 32;
  const int lane = tid & 63, w = tid >> 6;   // w = jt 0..9
  const int quad = lane >> 4, l16 = lane & 15;

  // init LDS state: h(-1) = 0 (also zeroes the j>=150 pad cols permanently)
  for (int i = tid; i < 3024; i += 640) ((s16x4*)ah)[i] = (s16x4){0, 0, 0, 0};
  for (int i = tid; i < 32 * 150; i += 640) hfl[i] = 0.f;

  const short* Bph[3];
  const short* Bpx[3];
#pragma unroll
  for (int g = 0; g < 3; ++g) {
    Bph[g] = Bh + (size_t)(g * 10 + w) * (KCH * 512) + lane * 8;
    Bpx[g] = Bx + (size_t)(g * 10 + w) * (KCX * 512) + lane * 8;
  }
  const int arh = l16 * 168 + quad * 8;
  const int arx = l16 * 72 + quad * 8;
  const int j = w * 16 + l16;

  __syncthreads();

  for (int t = 0; t < Tn; ++t) {
    const int cb = t & 1;
    short* ahc = ah[cb];
    short* ahn = ah[1 - cb];

    // refresh halo rows 0,1,34,35 of current window from global (neighbors' h)
    if (tid < 160) {
      int rr = tid / 40, c4 = (tid - rr * 40) * 4;
      int r = (rr < 2) ? rr : rr + 32;
      int l = l0 - 2 + r;
      s16x4 v = {0, 0, 0, 0};
      if (l >= 0 && l < Ln) v = *(const s16x4*)&hbG[((size_t)bb * Ln + l) * HP + c4];
      *(s16x4*)&ahc[r * 168 + c4] = v;
    }
    // stage x window for step t
    for (int i = tid; i < 36 * 16; i += 640) {
      int r = i >> 4, c4 = (i & 15) * 4;
      int l = l0 - 2 + r;
      s16x4 v = {0, 0, 0, 0};
      if (l >= 0 && l < Ln) {
        f32x4 f = *(const f32x4*)&xs[(((size_t)bb * Tn + t) * Ln + l) * Cn + c4];
        v[0] = f2bf(f[0]); v[1] = f2bf(f[1]); v[2] = f2bf(f[2]); v[3] = f2bf(f[3]);
      }
      *(s16x4*)&ax[r * 72 + c4] = v;
    }
    __syncthreads();

    f32x4 acc[2][3] = {};   // r | z | n(h-part)
    f32x4 axn[2] = {};      // n(x-part): n = tanh(iin + r*hin)

    // prime x-phase B loads early (independent of h loop)
    bf16x8 bxr[3][3];
#pragma unroll
    for (int s = 0; s < 2; ++s)
#pragma unroll
      for (int g = 0; g < 3; ++g) bxr[s][g] = *(const bf16x8*)(Bpx[g] + s * 512);

    bf16x8 bhr[4][3];   // 4-stage rolling prefetch
#pragma unroll
    for (int s = 0; s < 3; ++s)
#pragma unroll
      for (int g = 0; g < 3; ++g) bhr[s][g] = *(const bf16x8*)(Bph[g] + s * 512);

#pragma unroll
    for (int kc = 0; kc < KCH; ++kc) {
      const int cs = kc & 3;
      if (kc + 3 < KCH) {
        const int nx = (kc + 3) & 3;
#pragma unroll
        for (int g = 0; g < 3; ++g)
          bhr[nx][g] = *(const bf16x8*)(Bph[g] + (kc + 3) * 512);
      }
      const int kk = kc / 5, jj = (kc - kk * 5) * 32;
      const short* ar = &ahc[arh + kk * 168 + jj];
      bf16x8 a0 = *(const bf16x8*)(ar);
      bf16x8 a1 = *(const bf16x8*)(ar + 16 * 168);
#pragma unroll
      for (int g = 0; g < 3; ++g) {
        acc[0][g] = MFMA_B16(a0, bhr[cs][g], acc[0][g]);
        acc[1][g] = MFMA_B16(a1, bhr[cs][g], acc[1][g]);
      }
    }

#pragma unroll
    for (int kc = 0; kc < KCX; ++kc) {
      const int cs = kc % 3;
      if (kc + 2 < KCX) {
        const int nx = (kc + 2) % 3;
#pragma unroll
        for (int g = 0; g < 3; ++g)
          bxr[nx][g] = *(const bf16x8*)(Bpx[g] + (kc + 2) * 512);
      }
      const int kk = kc >> 1, jj = (kc & 1) * 32;
      const short* ar = &ax[arx + kk * 72 + jj];
      bf16x8 a0 = *(const bf16x8*)(ar);
      bf16x8 a1 = *(const bf16x8*)(ar + 16 * 72);
      acc[0][0] = MFMA_B16(a0, bxr[cs][0], acc[0][0]);
      acc[1][0] = MFMA_B16(a1, bxr[cs][0], acc[1][0]);
      acc[0][1] = MFMA_B16(a0, bxr[cs][1], acc[0][1]);
      acc[1][1] = MFMA_B16(a1, bxr[cs][1], acc[1][1]);
      axn[0]    = MFMA_B16(a0, bxr[cs][2], axn[0]);
      axn[1]    = MFMA_B16(a1, bxr[cs][2], axn[1]);
    }

    // Gates: lane covers j = w*16 + l16; m-rows ml = mi*16 + quad*4 + r.
    if (j < Hn) {
#pragma unroll
      for (int mi = 0; mi < 2; ++mi)
#pragma unroll
        for (int r = 0; r < 4; ++r) {
          const int ml = mi * 16 + quad * 4 + r;
          float rg = 1.f / (1.f + __expf(-acc[mi][0][r]));
          float zg = 1.f / (1.f + __expf(-acc[mi][1][r]));
          float xg = axn[mi][r] + rg * acc[mi][2][r];
          xg = fminf(fmaxf(xg, -15.f), 15.f);
          float e = __expf(2.f * xg);
          float n = (e - 1.f) / (e + 1.f);
          float hn = (1.f - zg) * n + zg * hfl[ml * 150 + j];
          hfl[ml * 150 + j] = hn;
          short hb = f2bf(hn);
          ahn[(ml + 2) * 168 + j] = hb;               // next step's A window (LDS)
          if (ml < 2 || ml >= 30)                      // boundary rows -> neighbors
            hbG[((size_t)bb * Ln + l0 + ml) * HP + j] = hb;
        }
    }
    __threadfence();
    grid.sync();
  }

  // dump final h for the head
  for (int i = tid; i < 32 * 150; i += 640) {
    int ml = i / 150, jj = i - ml * 150;
    hfG[((size_t)bb * Ln + l0 + ml) * Hn + jj] = hfl[i];
  }
}

// Head: thread-per-output fp32.
__global__ __launch_bounds__(256) void head1(const float* __restrict__ hf,
                                             const float* __restrict__ W1,
                                             const float* __restrict__ b1,
                                             float* __restrict__ hdn) {
  int idx = blockIdx.x * 256 + threadIdx.x;
  if (idx >= Mtot * Hn) return;
  int m = idx / Hn, j = idx - m * Hn;
  const float* hr = hf + (size_t)m * Hn;
  float acc = b1[j];
#pragma unroll 10
  for (int i = 0; i < Hn; ++i) acc = fmaf(hr[i], W1[i * Hn + j], acc);
  hdn[idx] = acc / (1.f + __expf(-acc));   // silu
}
__global__ __launch_bounds__(256) void head2(const float* __restrict__ hdn,
                                             const float* __restrict__ W2,
                                             const float* __restrict__ b2,
                                             float* __restrict__ out) {
  int idx = blockIdx.x * 256 + threadIdx.x;
  if (idx >= Mtot * 24) return;
  int m = idx / 24, j = idx - m * 24;
  const float* hr = hdn + (size_t)m * Hn;
  float acc = b2[j];
#pragma unroll 10
  for (int i = 0; i < Hn; ++i) acc = fmaf(hr[i], W2[i * 24 + j], acc);
  out[idx] = acc;
}

extern "C" void kernel_launch(void* const* d_in, const int* in_sizes, int n_in,
                              void* d_out, int out_size, void* d_ws, size_t ws_size,
                              hipStream_t stream) {
  const float* xs = (const float*)d_in[0];
  const float* ki = (const float*)d_in[1];
  const float* kh = (const float*)d_in[2];
  const float* W1 = (const float*)d_in[3];
  const float* b1 = (const float*)d_in[4];
  const float* W2 = (const float*)d_in[5];
  const float* b2 = (const float*)d_in[6];
  float* out = (float*)d_out;

  char* p = (char*)d_ws;
  float* hfG = (float*)p; p += (size_t)Mtot * Hn * 4;       // 4.7 MiB
  float* hdn = (float*)p; p += (size_t)Mtot * Hn * 4;       // 4.7 MiB
  short* hbG = (short*)p; p += (size_t)Mtot * HP * 2;       // 2.5 MiB
  short* Bh  = (short*)p; p += (size_t)32 * KCH * 512 * 2;  // 0.8 MiB
  short* Bx  = (short*)p; p += (size_t)32 * KCX * 512 * 2;  // 0.3 MiB

  hipMemsetAsync(hbG, 0, (size_t)Mtot * HP * 2, stream);    // pad cols stay 0
  pack_weights<<<(32 * (KCH + KCX) * 512 + 255) / 256, 256, 0, stream>>>(ki, kh, Bx, Bh);

  void* args[] = {(void*)&xs, (void*)&Bh, (void*)&Bx, (void*)&hbG, (void*)&hfG};
  hipLaunchCooperativeKernel((void*)gru_scan, dim3(256), dim3(640), args, 0, stream);

  head1<<<(Mtot * Hn + 255) / 256, 256, 0, stream>>>(hfG, W1, b1, hdn);
  head2<<<(Mtot * 24 + 255) / 256, 256, 0, stream>>>(hdn, W2, b2, out);
}